// Round 5
// baseline (149.824 us; speedup 1.0000x reference)
//
#include <hip/hip_runtime.h>

// TreeCRF belief propagation, B=2048, C=2, L=2048, BRANCH=4.
// ONE WAVE per batch element (64-thread blocks, 2048 blocks co-resident),
// wave-synchronous LDS -> ZERO __syncthreads. Round-3 evidence: VALU math
// is ~3 us; the ~40 us block-version time was barrier overhead (13 barriers
// x 8 sequential blocks/CU).
//
// LDS = 4 KB al[]: alpha/pb for INTERNAL nodes (0..511) only, interleaved
// [n*2+c]. Leaf alpha == 0 (select), leaf pb never consumed (skipped).
// No zero-init: every internal slot is written before it is read (in-order
// DS within the single wave).
//   upward:   al[n] <- alpha[n]   (each internal node written exactly once)
//   downward: al[n] <- pb[n] = em[n]+beta[n], read alpha first; children
//             only need pb[par]; score = alpha + pb.
// Emissions are read straight from global (coalesced, L2/L3-backed).
// Static tree: parent(i) = (i-1)>>2. Level starts {0,1,5,21,85,341,1365};
// internal 0..511 (node 511 has 3 children), leaves 512..2047.
// Per-edge tables precomputed into d_ws; exact LSE:
//   msg[yp] = A[yp] + l0 + ln2*log2(1 + 2^((l1-l0)*log2e) * E[yp])

constexpr int NLAB = 2048;
constexpr int NBATCH = 2048;

#define LOG2E 1.4426950408889634f
#define LN2   0.6931471805599453f

__device__ __forceinline__ float fexp2(float x) { return __builtin_amdgcn_exp2f(x); }
__device__ __forceinline__ float flog2(float x) { return __builtin_amdgcn_logf(x); }

// edge record {A0, A1, E0, E1}: A[yp]=t[yp][0], E[yp]=2^((t[yp][1]-t[yp][0])*log2e)
__global__ __launch_bounds__(256) void compact_pairs(
    const float4* __restrict__ pairs4,  // (L, L) of float4
    float4* __restrict__ up,            // pairs[parent(c)][c], [yp][yc]
    float4* __restrict__ down)          // pairs[c][parent(c)], [yc][yp]
{
    int i = blockIdx.x * 256 + threadIdx.x;
    if (i < NLAB - 1) {
        int c = i + 1, p = i >> 2;
        float4 t = pairs4[(size_t)p * NLAB + c];
        up[i] = make_float4(t.x, t.z,
                            fexp2((t.y - t.x) * LOG2E),
                            fexp2((t.w - t.z) * LOG2E));
        float4 s = pairs4[(size_t)c * NLAB + p];
        down[i] = make_float4(s.x, s.z,
                              fexp2((s.y - s.x) * LOG2E),
                              fexp2((s.w - s.z) * LOG2E));
    }
}

__global__ __launch_bounds__(64) void treecrf_kernel(
    const float* __restrict__ em_g,     // (B, 2, L)
    const float4* __restrict__ up,
    const float4* __restrict__ down,
    float* __restrict__ out)            // (B, 2, L)
{
    __shared__ float al[2 * 512];       // 4 KB: internal-node alpha, then pb
    float2* al2 = reinterpret_cast<float2*>(al);

    const int b = blockIdx.x;
    const int lane = threadIdx.x;
    const float* __restrict__ e0g = em_g + (size_t)b * 2 * NLAB;  // class 0
    const float* __restrict__ e1g = e0g + NLAB;                   // class 1

    // ---- upward pass (deep -> shallow), child-per-lane, wave-synchronous ----
    // i = child-1; parent = i>>2; all range starts are multiples of 4 so
    // sibling groups align with 4-lane groups. i=2047 (child 2048) is a
    // phantom -> msg forced to 0.
    const int ustart[6] = {1364, 340, 84, 20, 4, 0};
    const int uend[6]   = {2048, 1364, 340, 84, 20, 4};
#pragma unroll
    for (int pass = 0; pass < 6; ++pass) {
        for (int i = ustart[pass] + lane; i < uend[pass]; i += 64) {
            const bool valid = (i + 1) < NLAB;
            const int c = valid ? i + 1 : NLAB - 1;     // clamp loads
            float l0 = e0g[c];
            float l1 = e1g[c];
            if (pass > 0) {   // pass-0 children are all leaves: alpha == 0
                float2 a = al2[min(c, 511)];
                bool internal = c < 512;                // pass 1 mixes both
                l0 += internal ? a.x : 0.f;
                l1 += internal ? a.y : 0.f;
            }
            float4 t = up[min(i, NLAB - 2)];            // {A0, A1, E0, E1}
            float eu = fexp2((l1 - l0) * LOG2E);
            float m0 = t.x + l0 + LN2 * flog2(fmaf(eu, t.z, 1.f));
            float m1 = t.y + l0 + LN2 * flog2(fmaf(eu, t.w, 1.f));
            if (!valid) { m0 = 0.f; m1 = 0.f; }
            // sum the 4 siblings across the 4-lane group
            m0 += __shfl_xor(m0, 1, 4);  m0 += __shfl_xor(m0, 2, 4);
            m1 += __shfl_xor(m1, 1, 4);  m1 += __shfl_xor(m1, 2, 4);
            if ((i & 3) == 0)
                al2[i >> 2] = make_float2(m0, m1);      // parent is internal
        }
    }

    float* __restrict__ ob0 = out + (size_t)b * 2 * NLAB;
    float* __restrict__ ob1 = ob0 + NLAB;

    // ---- root: beta = 0 -> pb = em; emit output; stash pb in al2[0] ----
    if (lane == 0) {
        float pb0 = e0g[0];
        float pb1 = e1g[0];
        float s0 = pb0 + al[0];
        float s1 = pb1 + al[1];
        float Z = s0 + LN2 * flog2(1.f + fexp2((s1 - s0) * LOG2E));
        ob0[0] = s0 - Z;
        ob1[0] = s1 - Z;
        al2[0] = make_float2(pb0, pb1);
    }

    // ---- downward pass (shallow -> deep), node-per-lane, fused output ----
    // al2[par] holds pb[par] (written in the previous pass); al2[n] is read
    // (alpha) then overwritten with pb[n] iff n is internal.
    const int dstart[6] = {1, 5, 21, 85, 341, 1365};
    const int dend[6]   = {5, 21, 85, 341, 1365, 2048};
#pragma unroll
    for (int pass = 0; pass < 6; ++pass) {
        for (int n = dstart[pass] + lane; n < dend[pass]; n += 64) {
            const int par = (n - 1) >> 2;               // par <= 511 always
            float2 pp = al2[par];                       // pb[par]
            float4 t = down[n - 1];                     // {D0, D1, F0, F1}
            float eu = fexp2((pp.y - pp.x) * LOG2E);
            float m0 = t.x + pp.x + LN2 * flog2(fmaf(eu, t.z, 1.f));
            float m1 = t.y + pp.x + LN2 * flog2(fmaf(eu, t.w, 1.f));
            float a0 = 0.f, a1 = 0.f;                   // leaf alpha == 0
            if (pass < 5) {                             // passes with internals
                float2 a = al2[min(n, 511)];
                if (n < 512) { a0 = a.x; a1 = a.y; }
            }
            float pb0 = e0g[n] + m0;
            float pb1 = e1g[n] + m1;
            if (pass < 5 && n < 512)
                al2[n] = make_float2(pb0, pb1);         // pb for children
            float s0 = pb0 + a0;
            float s1 = pb1 + a1;
            float Z = s0 + LN2 * flog2(1.f + fexp2((s1 - s0) * LOG2E));
            ob0[n] = s0 - Z;
            ob1[n] = s1 - Z;
        }
    }
}

extern "C" void kernel_launch(void* const* d_in, const int* in_sizes, int n_in,
                              void* d_out, int out_size, void* d_ws, size_t ws_size,
                              hipStream_t stream) {
    const float*  emissions = (const float*)d_in[0];
    const float4* pairs4    = (const float4*)d_in[1];
    float* outp             = (float*)d_out;

    float4* upw = (float4*)d_ws;
    float4* dnw = upw + (NLAB - 1);
    compact_pairs<<<dim3((NLAB + 255) / 256), dim3(256), 0, stream>>>(pairs4, upw, dnw);
    treecrf_kernel<<<dim3(NBATCH), dim3(64), 0, stream>>>(emissions, upw, dnw, outp);
}

// Round 7
// 138.135 us; speedup vs baseline: 1.0846x; 1.0846x over previous
//
#include <hip/hip_runtime.h>

// TreeCRF belief propagation, B=2048, C=2, L=2048, BRANCH=4.
// ONE WAVE per batch element (64-thread blocks, 2048 blocks), ZERO barriers.
// Round-5 lesson: without LDS staging the wave is latency-bound (VGPR=16,
// VALUBusy 13.6%) -- global em loads serialized on the critical path.
// This round: stage em into LDS with 16 independent float4 loads up front,
// fully unroll every pass (compile-time trip counts, predicated tails).
//
// LDS/block = 20 KB: em[4096] interleaved [l*2+c] (16 KB) + al[1024] (4 KB,
// internal nodes 0..511 only: alpha in the up pass, overwritten with
// pb = em+beta in the down pass after alpha is consumed).
// Static tree: parent(i) = (i-1)>>2. Level starts {0,1,5,21,85,341,1365};
// internal 0..511 (node 511 has 3 children), leaves 512..2047.
// Per-edge tables precomputed into d_ws; exact LSE:
//   msg[yp] = A[yp] + l0 + ln2*log2(1 + 2^((l1-l0)*log2e) * E[yp])

constexpr int NLAB = 2048;
constexpr int NBATCH = 2048;

#define LOG2E 1.4426950408889634f
#define LN2   0.6931471805599453f

__device__ __forceinline__ float fexp2(float x) { return __builtin_amdgcn_exp2f(x); }
__device__ __forceinline__ float flog2(float x) { return __builtin_amdgcn_logf(x); }

// edge record {A0, A1, E0, E1}: A[yp]=t[yp][0], E[yp]=2^((t[yp][1]-t[yp][0])*log2e)
__global__ __launch_bounds__(256) void compact_pairs(
    const float4* __restrict__ pairs4,  // (L, L) of float4
    float4* __restrict__ up,            // pairs[parent(c)][c], [yp][yc]
    float4* __restrict__ down)          // pairs[c][parent(c)], [yc][yp]
{
    int i = blockIdx.x * 256 + threadIdx.x;
    if (i < NLAB - 1) {
        int c = i + 1, p = i >> 2;
        float4 t = pairs4[(size_t)p * NLAB + c];
        up[i] = make_float4(t.x, t.z,
                            fexp2((t.y - t.x) * LOG2E),
                            fexp2((t.w - t.z) * LOG2E));
        float4 s = pairs4[(size_t)c * NLAB + p];
        down[i] = make_float4(s.x, s.z,
                              fexp2((s.y - s.x) * LOG2E),
                              fexp2((s.w - s.z) * LOG2E));
    }
}

__global__ __launch_bounds__(64, 2) void treecrf_kernel(
    const float* __restrict__ em_g,     // (B, 2, L)
    const float4* __restrict__ up,
    const float4* __restrict__ down,
    float* __restrict__ out)            // (B, 2, L)
{
    __shared__ float em[2 * NLAB];      // 16 KB, interleaved [l*2+c]
    __shared__ float al[2 * 512];       // 4 KB, internal alpha -> pb

    const int b = blockIdx.x;
    const int lane = threadIdx.x;
    const float4* __restrict__ eg4 =
        reinterpret_cast<const float4*>(em_g + (size_t)b * 2 * NLAB);
    float4* em4 = reinterpret_cast<float4*>(em);
    const float2* em2 = reinterpret_cast<const float2*>(em);
    float2* al2 = reinterpret_cast<float2*>(al);

    // ---- stage emissions -> LDS interleaved: 16 independent float4 loads ----
#pragma unroll
    for (int k = 0; k < 8; ++k) {
        int j = k * 64 + lane;                  // float4 index in class, 0..511
        float4 a0 = eg4[j];                     // class 0, labels 4j..4j+3
        float4 a1 = eg4[512 + j];               // class 1, labels 4j..4j+3
        em4[2 * j]     = make_float4(a0.x, a1.x, a0.y, a1.y);
        em4[2 * j + 1] = make_float4(a0.z, a1.z, a0.w, a1.w);
    }
    // single wave: DS ops are in-order, no barrier needed

    // ---- upward pass (deep -> shallow), child-per-lane ----
    // i = child-1; parent = i>>2; range starts are multiples of 4 so sibling
    // quads align with 4-lane groups. i=2047 (child 2048) is a phantom.
    const int ustart[6] = {1364, 340, 84, 20, 4, 0};
    const int ucnt[6]   = {684, 1024, 256, 64, 16, 4};
#pragma unroll
    for (int pass = 0; pass < 6; ++pass) {
        const int s = ustart[pass];
        const int iters = (ucnt[pass] + 63) >> 6;
#pragma unroll
        for (int k = 0; k < iters; ++k) {
            const int i = s + k * 64 + lane;
            const bool active = (i - s) < ucnt[pass];
            const bool valid = active && (i + 1) < NLAB;
            const int c = min(i + 1, NLAB - 1);     // clamped loads
            float2 e = em2[c];
            float l0 = e.x, l1 = e.y;
            if (pass == 1) {                 // mixed internal/leaf children
                float2 a = al2[min(c, 511)];
                if (c < 512) { l0 += a.x; l1 += a.y; }
            } else if (pass >= 2) {          // all-internal children (c<=340)
                float2 a = al2[c];
                l0 += a.x; l1 += a.y;
            }                                // pass 0: all leaves, alpha==0
            float4 t = up[min(i, NLAB - 2)];        // {A0, A1, E0, E1}
            float eu = fexp2((l1 - l0) * LOG2E);
            float m0 = t.x + l0 + LN2 * flog2(fmaf(eu, t.z, 1.f));
            float m1 = t.y + l0 + LN2 * flog2(fmaf(eu, t.w, 1.f));
            if (!valid) { m0 = 0.f; m1 = 0.f; }
            // sum the 4 siblings across the 4-lane group
            m0 += __shfl_xor(m0, 1, 4);  m0 += __shfl_xor(m0, 2, 4);
            m1 += __shfl_xor(m1, 1, 4);  m1 += __shfl_xor(m1, 2, 4);
            if (active && (i & 3) == 0)
                al2[i >> 2] = make_float2(m0, m1);  // parent is internal
        }
    }

    float* __restrict__ ob0 = out + (size_t)b * 2 * NLAB;
    float* __restrict__ ob1 = ob0 + NLAB;

    // ---- root: beta = 0 -> pb = em; emit output; stash pb in al2[0] ----
    if (lane == 0) {
        float2 e = em2[0];
        float s0 = e.x + al[0];
        float s1 = e.y + al[1];
        float Z = s0 + LN2 * flog2(1.f + fexp2((s1 - s0) * LOG2E));
        ob0[0] = s0 - Z;
        ob1[0] = s1 - Z;
        al2[0] = make_float2(e.x, e.y);
    }

    // ---- downward pass (shallow -> deep), node-per-lane, fused output ----
    // al2[par] holds pb[par] (previous pass); al2[n] is read (alpha) then
    // overwritten with pb[n] iff n is internal.
    const int dstart[6] = {1, 5, 21, 85, 341, 1365};
    const int dcnt[6]   = {4, 16, 64, 256, 1024, 683};
#pragma unroll
    for (int pass = 0; pass < 6; ++pass) {
        const int s = dstart[pass];
        const int iters = (dcnt[pass] + 63) >> 6;
#pragma unroll
        for (int k = 0; k < iters; ++k) {
            const int n = s + k * 64 + lane;
            const bool active = (n - s) < dcnt[pass];
            const int nc = active ? n : s;          // clamped index
            const int par = (nc - 1) >> 2;          // par <= 511 always
            float2 pp = al2[par];                   // pb[par] (broadcast read)
            float4 t = down[nc - 1];                // {D0, D1, F0, F1}
            float eu = fexp2((pp.y - pp.x) * LOG2E);
            float m0 = t.x + pp.x + LN2 * flog2(fmaf(eu, t.z, 1.f));
            float m1 = t.y + pp.x + LN2 * flog2(fmaf(eu, t.w, 1.f));
            float2 e = em2[nc];
            float pb0 = e.x + m0;
            float pb1 = e.y + m1;
            float a0 = 0.f, a1 = 0.f;
            if (pass <= 3) {                        // all internal (n<=340)
                float2 a = al2[nc];
                a0 = a.x; a1 = a.y;
                if (active) al2[nc] = make_float2(pb0, pb1);
            } else if (pass == 4) {                 // mixed internal/leaf
                float2 a = al2[min(nc, 511)];
                if (nc < 512) {
                    a0 = a.x; a1 = a.y;
                    if (active) al2[nc] = make_float2(pb0, pb1);
                }
            }                                       // pass 5: all leaves
            float s0 = pb0 + a0;
            float s1 = pb1 + a1;
            float Z = s0 + LN2 * flog2(1.f + fexp2((s1 - s0) * LOG2E));
            if (active) {
                ob0[n] = s0 - Z;
                ob1[n] = s1 - Z;
            }
        }
    }
}

extern "C" void kernel_launch(void* const* d_in, const int* in_sizes, int n_in,
                              void* d_out, int out_size, void* d_ws, size_t ws_size,
                              hipStream_t stream) {
    const float*  emissions = (const float*)d_in[0];
    const float4* pairs4    = (const float4*)d_in[1];
    float* outp             = (float*)d_out;

    float4* upw = (float4*)d_ws;
    float4* dnw = upw + (NLAB - 1);
    compact_pairs<<<dim3((NLAB + 255) / 256), dim3(256), 0, stream>>>(pairs4, upw, dnw);
    treecrf_kernel<<<dim3(NBATCH), dim3(64), 0, stream>>>(emissions, upw, dnw, outp);
}

// Round 9
// 130.505 us; speedup vs baseline: 1.1480x; 1.0585x over previous
//
#include <hip/hip_runtime.h>

// TreeCRF belief propagation, B=2048, C=2, L=2048, BRANCH=4.
// Round-8 structure: 256-thread blocks (4 waves) per batch element; each
// WAVE owns one of the 4 independent depth-1 subtrees (wave-synchronous
// LDS within a subtree -> only 3 block barriers: stage / pre-root / post-root).
// 20480 B LDS -> 8 blocks/CU -> up to 32 waves/CU (vs 8 for 1-wave blocks,
// which round-5/7 showed is latency-bound at ~40 us, VALUBusy 14%).
// Subtree 0 holds all 683 depth-6 leaves (3x work) -> rotate subtree
// assignment by blockIdx so heavy waves spread across SIMDs.
//
// Tree: parent(i) = (i-1)>>2; levels start {0,1,5,21,85,341,1365};
// internal 0..511 (node 511 has 3 children), leaves 512..2047.
// Subtree k (root child 1+k): d2 5+4k.., d3 21+16k.. (16), d4 85+64k.. (64),
// d5 341+256k.. (256, k=0 mixed internal/leaf), d6 1365..2047 (k=0 only).
// Per-edge tables precomputed into d_ws; exact 2-class LSE:
//   msg[yp] = A[yp] + l0 + ln2*log2(1 + 2^((l1-l0)*log2e) * E[yp])

constexpr int NLAB = 2048;
constexpr int NBATCH = 2048;

#define LOG2E 1.4426950408889634f
#define LN2   0.6931471805599453f

__device__ __forceinline__ float fexp2(float x) { return __builtin_amdgcn_exp2f(x); }
__device__ __forceinline__ float flog2(float x) { return __builtin_amdgcn_logf(x); }

// edge record {A0, A1, E0, E1}: A[yp]=t[yp][0], E[yp]=2^((t[yp][1]-t[yp][0])*log2e)
__global__ __launch_bounds__(256) void compact_pairs(
    const float4* __restrict__ pairs4,  // (L, L) of float4
    float4* __restrict__ up,            // pairs[parent(c)][c], [yp][yc]
    float4* __restrict__ down)          // pairs[c][parent(c)], [yc][yp]
{
    int i = blockIdx.x * 256 + threadIdx.x;
    if (i < NLAB - 1) {
        int c = i + 1, p = i >> 2;
        float4 t = pairs4[(size_t)p * NLAB + c];
        up[i] = make_float4(t.x, t.z,
                            fexp2((t.y - t.x) * LOG2E),
                            fexp2((t.w - t.z) * LOG2E));
        float4 s = pairs4[(size_t)c * NLAB + p];
        down[i] = make_float4(s.x, s.z,
                              fexp2((s.y - s.x) * LOG2E),
                              fexp2((s.w - s.z) * LOG2E));
    }
}

// up message for child index i (child = i+1). AMODE: 0 leaf-child, 1 mixed
// (alpha iff child<512), 2 all-internal. Returns the 4-sibling-reduced msg.
template <int AMODE>
__device__ __forceinline__ float2 up_step(int i, bool active,
        const float2* em2, float2* al2, const float4* __restrict__ upt) {
    const bool valid = active && (i + 1) < NLAB;
    const int c = min(i + 1, NLAB - 1);
    float2 e = em2[c];
    float l0 = e.x, l1 = e.y;
    if (AMODE == 2) { float2 a = al2[c]; l0 += a.x; l1 += a.y; }
    if (AMODE == 1) { float2 a = al2[min(c, 511)];
                      if (c < 512) { l0 += a.x; l1 += a.y; } }
    float4 t = upt[min(i, NLAB - 2)];          // {A0, A1, E0, E1}
    float eu = fexp2((l1 - l0) * LOG2E);
    float m0 = t.x + l0 + LN2 * flog2(fmaf(eu, t.z, 1.f));
    float m1 = t.y + l0 + LN2 * flog2(fmaf(eu, t.w, 1.f));
    if (!valid) { m0 = 0.f; m1 = 0.f; }
    m0 += __shfl_xor(m0, 1, 4);  m0 += __shfl_xor(m0, 2, 4);
    m1 += __shfl_xor(m1, 1, 4);  m1 += __shfl_xor(m1, 2, 4);
    if (active && (i & 3) == 0) al2[i >> 2] = make_float2(m0, m1);
    return make_float2(m0, m1);
}

// down step for node n. DMODE: 2 internal (read alpha, write pb), 1 mixed
// (iff n<512), 0 leaf (no alpha, no pb write).
template <int DMODE>
__device__ __forceinline__ void down_step(int n, bool active,
        const float2* em2, float2* al2, const float4* __restrict__ dnt,
        float* __restrict__ ob0, float* __restrict__ ob1) {
    const int nc = min(n, NLAB - 1);
    const int par = (nc - 1) >> 2;              // <= 511 always
    float2 pp = al2[par];                       // pb[par]
    float4 t = dnt[nc - 1];                     // {D0, D1, F0, F1}
    float eu = fexp2((pp.y - pp.x) * LOG2E);
    float m0 = t.x + pp.x + LN2 * flog2(fmaf(eu, t.z, 1.f));
    float m1 = t.y + pp.x + LN2 * flog2(fmaf(eu, t.w, 1.f));
    float2 e = em2[nc];
    float pb0 = e.x + m0, pb1 = e.y + m1;
    float a0 = 0.f, a1 = 0.f;
    if (DMODE == 2) {
        float2 a = al2[nc]; a0 = a.x; a1 = a.y;
        if (active) al2[nc] = make_float2(pb0, pb1);
    }
    if (DMODE == 1) {
        float2 a = al2[min(nc, 511)];
        if (nc < 512) { a0 = a.x; a1 = a.y; }
        if (active && nc < 512) al2[nc] = make_float2(pb0, pb1);
    }
    float s0 = pb0 + a0, s1 = pb1 + a1;
    float Z = s0 + LN2 * flog2(1.f + fexp2((s1 - s0) * LOG2E));
    if (active) { ob0[n] = s0 - Z; ob1[n] = s1 - Z; }
}

__global__ __launch_bounds__(256, 4) void treecrf_kernel(
    const float* __restrict__ em_g,     // (B, 2, L)
    const float4* __restrict__ up,
    const float4* __restrict__ down,
    float* __restrict__ out)            // (B, 2, L)
{
    __shared__ float em[2 * NLAB];      // 16 KB, interleaved [l*2+c]
    __shared__ float al[2 * 512];       // 4 KB, internal alpha -> pb (total 20480 B)

    const int b = blockIdx.x;
    const int tid = threadIdx.x;
    const int lane = tid & 63;
    const int w = tid >> 6;
    const int k = (w + b) & 3;          // rotated subtree assignment

    const float4* __restrict__ eg4 =
        reinterpret_cast<const float4*>(em_g + (size_t)b * 2 * NLAB);
    float4* em4 = reinterpret_cast<float4*>(em);
    const float2* em2 = reinterpret_cast<const float2*>(em);
    float2* al2 = reinterpret_cast<float2*>(al);

    // ---- stage emissions -> LDS interleaved (all 256 threads) ----
#pragma unroll
    for (int it = 0; it < 2; ++it) {
        int j = it * 256 + tid;                 // float4 index in class, 0..511
        float4 a0 = eg4[j];                     // class 0, labels 4j..4j+3
        float4 a1 = eg4[512 + j];               // class 1
        em4[2 * j]     = make_float4(a0.x, a1.x, a0.y, a1.y);
        em4[2 * j + 1] = make_float4(a0.z, a1.z, a0.w, a1.w);
    }
    __syncthreads();                            // barrier 1

    // ---- UP, wave-local on subtree k (deep -> shallow) ----
    if (k == 0) {
#pragma unroll 4
        for (int it = 0; it < 11; ++it) {       // d6 children 1365..2048(ph)
            int i = 1364 + it * 64 + lane;
            up_step<0>(i, i < 2048, em2, al2, up);
        }
#pragma unroll
        for (int it = 0; it < 4; ++it)          // d5 children 341..596 mixed
            up_step<1>(340 + it * 64 + lane, true, em2, al2, up);
    } else {
        const int ib = 340 + 256 * k;
#pragma unroll
        for (int it = 0; it < 4; ++it)          // d5 children all leaves
            up_step<0>(ib + it * 64 + lane, true, em2, al2, up);
    }
    up_step<2>(84 + 64 * k + lane, true, em2, al2, up);        // d4 children
    up_step<2>(20 + 16 * k + lane, lane < 16, em2, al2, up);   // d3 children
    float2 acc = up_step<2>(4 + 4 * k + lane, lane < 4, em2, al2, up); // d2
    // lanes 0..3 now hold alpha[1+k] in acc (kept in registers)
    const float alpha0 = acc.x, alpha1 = acc.y;

    if (lane == 0) {                    // message (1+k) -> root
        float2 e = em2[1 + k];
        float l0 = e.x + alpha0, l1 = e.y + alpha1;
        float4 t = up[k];               // child index i = k
        float eu = fexp2((l1 - l0) * LOG2E);
        float m0 = t.x + l0 + LN2 * flog2(fmaf(eu, t.z, 1.f));
        float m1 = t.y + l0 + LN2 * flog2(fmaf(eu, t.w, 1.f));
        al2[1 + k] = make_float2(m0, m1);   // overwrite alpha with msg
    }
    __syncthreads();                            // barrier 2

    float* __restrict__ ob0 = out + (size_t)b * 2 * NLAB;
    float* __restrict__ ob1 = ob0 + NLAB;

    if (tid == 0) {                     // root combine: alpha0 = sum of msgs
        float2 q1 = al2[1], q2 = al2[2], q3 = al2[3], q4 = al2[4];
        float ra0 = (q1.x + q2.x) + (q3.x + q4.x);
        float ra1 = (q1.y + q2.y) + (q3.y + q4.y);
        float2 e = em2[0];
        float s0 = e.x + ra0, s1 = e.y + ra1;
        float Z = s0 + LN2 * flog2(1.f + fexp2((s1 - s0) * LOG2E));
        ob0[0] = s0 - Z;  ob1[0] = s1 - Z;
        al2[0] = make_float2(e.x, e.y);         // pb[0] (beta = 0)
    }
    __syncthreads();                            // barrier 3

    // ---- DOWN, wave-local on subtree k (shallow -> deep) ----
    if (lane == 0) {                    // node 1+k: alpha from registers
        const int n = 1 + k;
        float2 pp = al2[0];
        float4 t = down[k];
        float eu = fexp2((pp.y - pp.x) * LOG2E);
        float m0 = t.x + pp.x + LN2 * flog2(fmaf(eu, t.z, 1.f));
        float m1 = t.y + pp.x + LN2 * flog2(fmaf(eu, t.w, 1.f));
        float2 e = em2[n];
        float pb0 = e.x + m0, pb1 = e.y + m1;
        al2[n] = make_float2(pb0, pb1);         // pb for d2 children
        float s0 = pb0 + alpha0, s1 = pb1 + alpha1;
        float Z = s0 + LN2 * flog2(1.f + fexp2((s1 - s0) * LOG2E));
        ob0[n] = s0 - Z;  ob1[n] = s1 - Z;
    }
    down_step<2>(5 + 4 * k + lane, lane < 4, em2, al2, down, ob0, ob1);   // d2
    down_step<2>(21 + 16 * k + lane, lane < 16, em2, al2, down, ob0, ob1);// d3
    down_step<2>(85 + 64 * k + lane, true, em2, al2, down, ob0, ob1);     // d4
    if (k == 0) {
#pragma unroll
        for (int it = 0; it < 4; ++it)          // d5 341..596 mixed
            down_step<1>(341 + it * 64 + lane, true, em2, al2, down, ob0, ob1);
#pragma unroll 4
        for (int it = 0; it < 11; ++it) {       // d6 leaves 1365..2047
            int n = 1365 + it * 64 + lane;
            down_step<0>(n, n < 2048, em2, al2, down, ob0, ob1);
        }
    } else {
        const int nb = 341 + 256 * k;
#pragma unroll
        for (int it = 0; it < 4; ++it)          // d5 leaves
            down_step<0>(nb + it * 64 + lane, true, em2, al2, down, ob0, ob1);
    }
}

extern "C" void kernel_launch(void* const* d_in, const int* in_sizes, int n_in,
                              void* d_out, int out_size, void* d_ws, size_t ws_size,
                              hipStream_t stream) {
    const float*  emissions = (const float*)d_in[0];
    const float4* pairs4    = (const float4*)d_in[1];
    float* outp             = (float*)d_out;

    float4* upw = (float4*)d_ws;
    float4* dnw = upw + (NLAB - 1);
    compact_pairs<<<dim3((NLAB + 255) / 256), dim3(256), 0, stream>>>(pairs4, upw, dnw);
    treecrf_kernel<<<dim3(NBATCH), dim3(256), 0, stream>>>(emissions, upw, dnw, outp);
}

// Round 10
// 127.674 us; speedup vs baseline: 1.1735x; 1.0222x over previous
//
#include <hip/hip_runtime.h>

// TreeCRF belief propagation, B=2048, C=2, L=2048, BRANCH=4.
// Round-10: 256-thread blocks (4 waves)/batch elem; waves own the 4
// independent depth-1 subtrees, BUT the 683-leaf d6 level (all in subtree 0)
// is split across ALL 4 waves in both passes -> every wave runs ~10 level
// steps (was 18 heavy / 7 light against 3 barriers). 5 barriers total.
// __launch_bounds__(256,8) caps VGPR at 64 -> 8 blocks/CU resident
// (20480 B LDS x 8 = 160 KiB exactly), 32 waves/CU.
//
// Tree: parent(i) = (i-1)>>2; levels start {0,1,5,21,85,341,1365};
// internal 0..511 (node 511 has 3 children: 2045..2047), leaves 512..2047.
// Subtree k (root child 1+k): d2 i=4+4k, d3 i=20+16k (16), d4 i=84+64k (64),
// d5 i=340+256k (256; k=0 children mixed internal/leaf), d6 k=0 only.
// d6 split (i = child-1, quad-aligned): w0 [1364,1536) w1 [1536,1708)
// w2 [1708,1880) w3 [1880,2048) -> parent ranges disjoint (341..383/384..
// 426/427..469/470..511).
// Per-edge tables precomputed into d_ws; exact 2-class LSE:
//   msg[yp] = A[yp] + l0 + ln2*log2(1 + 2^((l1-l0)*log2e) * E[yp])

constexpr int NLAB = 2048;
constexpr int NBATCH = 2048;

#define LOG2E 1.4426950408889634f
#define LN2   0.6931471805599453f

__device__ __forceinline__ float fexp2(float x) { return __builtin_amdgcn_exp2f(x); }
__device__ __forceinline__ float flog2(float x) { return __builtin_amdgcn_logf(x); }

// edge record {A0, A1, E0, E1}: A[yp]=t[yp][0], E[yp]=2^((t[yp][1]-t[yp][0])*log2e)
__global__ __launch_bounds__(256) void compact_pairs(
    const float4* __restrict__ pairs4,  // (L, L) of float4
    float4* __restrict__ up,            // pairs[parent(c)][c], [yp][yc]
    float4* __restrict__ down)          // pairs[c][parent(c)], [yc][yp]
{
    int i = blockIdx.x * 256 + threadIdx.x;
    if (i < NLAB - 1) {
        int c = i + 1, p = i >> 2;
        float4 t = pairs4[(size_t)p * NLAB + c];
        up[i] = make_float4(t.x, t.z,
                            fexp2((t.y - t.x) * LOG2E),
                            fexp2((t.w - t.z) * LOG2E));
        float4 s = pairs4[(size_t)c * NLAB + p];
        down[i] = make_float4(s.x, s.z,
                              fexp2((s.y - s.x) * LOG2E),
                              fexp2((s.w - s.z) * LOG2E));
    }
}

// up message for child index i (child = i+1). AMODE: 0 leaf-child, 1 mixed
// (alpha iff child<512), 2 all-internal. Returns the 4-sibling-reduced msg.
template <int AMODE>
__device__ __forceinline__ float2 up_step(int i, bool active,
        const float2* em2, float2* al2, const float4* __restrict__ upt) {
    const bool valid = active && (i + 1) < NLAB;
    const int c = min(i + 1, NLAB - 1);
    float2 e = em2[c];
    float l0 = e.x, l1 = e.y;
    if (AMODE == 2) { float2 a = al2[c]; l0 += a.x; l1 += a.y; }
    if (AMODE == 1) { float2 a = al2[min(c, 511)];
                      if (c < 512) { l0 += a.x; l1 += a.y; } }
    float4 t = upt[min(i, NLAB - 2)];          // {A0, A1, E0, E1}
    float eu = fexp2((l1 - l0) * LOG2E);
    float m0 = t.x + l0 + LN2 * flog2(fmaf(eu, t.z, 1.f));
    float m1 = t.y + l0 + LN2 * flog2(fmaf(eu, t.w, 1.f));
    if (!valid) { m0 = 0.f; m1 = 0.f; }
    m0 += __shfl_xor(m0, 1, 4);  m0 += __shfl_xor(m0, 2, 4);
    m1 += __shfl_xor(m1, 1, 4);  m1 += __shfl_xor(m1, 2, 4);
    if (active && (i & 3) == 0) al2[i >> 2] = make_float2(m0, m1);
    return make_float2(m0, m1);
}

// down step for node n. DMODE: 2 internal (read alpha, write pb), 1 mixed
// (iff n<512), 0 leaf (no alpha, no pb write).
template <int DMODE>
__device__ __forceinline__ void down_step(int n, bool active,
        const float2* em2, float2* al2, const float4* __restrict__ dnt,
        float* __restrict__ ob0, float* __restrict__ ob1) {
    const int nc = min(n, NLAB - 1);
    const int par = (nc - 1) >> 2;              // <= 511 always
    float2 pp = al2[par];                       // pb[par]
    float4 t = dnt[nc - 1];                     // {D0, D1, F0, F1}
    float eu = fexp2((pp.y - pp.x) * LOG2E);
    float m0 = t.x + pp.x + LN2 * flog2(fmaf(eu, t.z, 1.f));
    float m1 = t.y + pp.x + LN2 * flog2(fmaf(eu, t.w, 1.f));
    float2 e = em2[nc];
    float pb0 = e.x + m0, pb1 = e.y + m1;
    float a0 = 0.f, a1 = 0.f;
    if (DMODE == 2) {
        float2 a = al2[nc]; a0 = a.x; a1 = a.y;
        if (active) al2[nc] = make_float2(pb0, pb1);
    }
    if (DMODE == 1) {
        float2 a = al2[min(nc, 511)];
        if (nc < 512) { a0 = a.x; a1 = a.y; }
        if (active && nc < 512) al2[nc] = make_float2(pb0, pb1);
    }
    float s0 = pb0 + a0, s1 = pb1 + a1;
    float Z = s0 + LN2 * flog2(1.f + fexp2((s1 - s0) * LOG2E));
    if (active) { ob0[n] = s0 - Z; ob1[n] = s1 - Z; }
}

__global__ __launch_bounds__(256, 8) void treecrf_kernel(
    const float* __restrict__ em_g,     // (B, 2, L)
    const float4* __restrict__ up,
    const float4* __restrict__ down,
    float* __restrict__ out)            // (B, 2, L)
{
    __shared__ float em[2 * NLAB];      // 16 KB, interleaved [l*2+c]
    __shared__ float al[2 * 512];       // 4 KB, internal alpha -> pb (20480 B)

    const int b = blockIdx.x;
    const int tid = threadIdx.x;
    const int lane = tid & 63;
    const int w = tid >> 6;
    const int k = (w + b) & 3;          // rotated subtree assignment

    const float4* __restrict__ eg4 =
        reinterpret_cast<const float4*>(em_g + (size_t)b * 2 * NLAB);
    float4* em4 = reinterpret_cast<float4*>(em);
    const float2* em2 = reinterpret_cast<const float2*>(em);
    float2* al2 = reinterpret_cast<float2*>(al);

    // ---- stage emissions -> LDS interleaved (all 256 threads) ----
#pragma unroll
    for (int it = 0; it < 2; ++it) {
        int j = it * 256 + tid;                 // float4 index in class, 0..511
        float4 a0 = eg4[j];                     // class 0, labels 4j..4j+3
        float4 a1 = eg4[512 + j];               // class 1
        em4[2 * j]     = make_float4(a0.x, a1.x, a0.y, a1.y);
        em4[2 * j + 1] = make_float4(a0.z, a1.z, a0.w, a1.w);
    }
    __syncthreads();                            // B1: em staged

    // ---- d6 UP, split across ALL 4 waves (balanced) ----
    {
        const int s6 = 1364 + 172 * w;          // 1364/1536/1708/1880
        const int c6 = (w == 3) ? 168 : 172;    // incl. phantom i=2047
#pragma unroll
        for (int it = 0; it < 3; ++it) {
            int i = s6 + it * 64 + lane;
            up_step<0>(i, (i - s6) < c6, em2, al2, up);
        }
    }
    __syncthreads();                            // B2: al2[341..511] ready

    // ---- subtree UP, wave-local (deep -> shallow) ----
    if (k == 0) {
#pragma unroll
        for (int it = 0; it < 4; ++it)          // d5 children 341..596 mixed
            up_step<1>(340 + it * 64 + lane, true, em2, al2, up);
    } else {
        const int ib = 340 + 256 * k;
#pragma unroll
        for (int it = 0; it < 4; ++it)          // d5 children all leaves
            up_step<0>(ib + it * 64 + lane, true, em2, al2, up);
    }
    up_step<2>(84 + 64 * k + lane, true, em2, al2, up);        // d4 children
    up_step<2>(20 + 16 * k + lane, lane < 16, em2, al2, up);   // d3 children
    float2 acc = up_step<2>(4 + 4 * k + lane, lane < 4, em2, al2, up); // d2
    // lanes 0..3 hold alpha[1+k] in acc (kept in registers)
    const float alpha0 = acc.x, alpha1 = acc.y;

    if (lane == 0) {                    // message (1+k) -> root
        float2 e = em2[1 + k];
        float l0 = e.x + alpha0, l1 = e.y + alpha1;
        float4 t = up[k];               // child index i = k
        float eu = fexp2((l1 - l0) * LOG2E);
        float m0 = t.x + l0 + LN2 * flog2(fmaf(eu, t.z, 1.f));
        float m1 = t.y + l0 + LN2 * flog2(fmaf(eu, t.w, 1.f));
        al2[1 + k] = make_float2(m0, m1);   // overwrite alpha with msg
    }
    __syncthreads();                            // B3

    float* __restrict__ ob0 = out + (size_t)b * 2 * NLAB;
    float* __restrict__ ob1 = ob0 + NLAB;

    if (tid == 0) {                     // root combine
        float2 q1 = al2[1], q2 = al2[2], q3 = al2[3], q4 = al2[4];
        float ra0 = (q1.x + q2.x) + (q3.x + q4.x);
        float ra1 = (q1.y + q2.y) + (q3.y + q4.y);
        float2 e = em2[0];
        float s0 = e.x + ra0, s1 = e.y + ra1;
        float Z = s0 + LN2 * flog2(1.f + fexp2((s1 - s0) * LOG2E));
        ob0[0] = s0 - Z;  ob1[0] = s1 - Z;
        al2[0] = make_float2(e.x, e.y);         // pb[0] (beta = 0)
    }
    __syncthreads();                            // B4

    // ---- subtree DOWN, wave-local (shallow -> deep) ----
    if (lane == 0) {                    // node 1+k: alpha from registers
        const int n = 1 + k;
        float2 pp = al2[0];
        float4 t = down[k];
        float eu = fexp2((pp.y - pp.x) * LOG2E);
        float m0 = t.x + pp.x + LN2 * flog2(fmaf(eu, t.z, 1.f));
        float m1 = t.y + pp.x + LN2 * flog2(fmaf(eu, t.w, 1.f));
        float2 e = em2[n];
        float pb0 = e.x + m0, pb1 = e.y + m1;
        al2[n] = make_float2(pb0, pb1);         // pb for d2 children
        float s0 = pb0 + alpha0, s1 = pb1 + alpha1;
        float Z = s0 + LN2 * flog2(1.f + fexp2((s1 - s0) * LOG2E));
        ob0[n] = s0 - Z;  ob1[n] = s1 - Z;
    }
    down_step<2>(5 + 4 * k + lane, lane < 4, em2, al2, down, ob0, ob1);   // d2
    down_step<2>(21 + 16 * k + lane, lane < 16, em2, al2, down, ob0, ob1);// d3
    down_step<2>(85 + 64 * k + lane, true, em2, al2, down, ob0, ob1);     // d4
    if (k == 0) {
#pragma unroll
        for (int it = 0; it < 4; ++it)          // d5 341..596 mixed
            down_step<1>(341 + it * 64 + lane, true, em2, al2, down, ob0, ob1);
    } else {
        const int nb = 341 + 256 * k;
#pragma unroll
        for (int it = 0; it < 4; ++it)          // d5 leaves
            down_step<0>(nb + it * 64 + lane, true, em2, al2, down, ob0, ob1);
    }
    __syncthreads();                            // B5: pb[341..511] ready

    // ---- d6 DOWN, split across ALL 4 waves ----
    {
        const int s6 = 1365 + 172 * w;          // 1365/1537/1709/1881
        const int c6 = (w == 3) ? 167 : 172;
#pragma unroll
        for (int it = 0; it < 3; ++it) {
            int n = s6 + it * 64 + lane;
            down_step<0>(n, (n - s6) < c6, em2, al2, down, ob0, ob1);
        }
    }
}

extern "C" void kernel_launch(void* const* d_in, const int* in_sizes, int n_in,
                              void* d_out, int out_size, void* d_ws, size_t ws_size,
                              hipStream_t stream) {
    const float*  emissions = (const float*)d_in[0];
    const float4* pairs4    = (const float4*)d_in[1];
    float* outp             = (float*)d_out;

    float4* upw = (float4*)d_ws;
    float4* dnw = upw + (NLAB - 1);
    compact_pairs<<<dim3((NLAB + 255) / 256), dim3(256), 0, stream>>>(pairs4, upw, dnw);
    treecrf_kernel<<<dim3(NBATCH), dim3(256), 0, stream>>>(emissions, upw, dnw, outp);
}

// Round 12
// 127.585 us; speedup vs baseline: 1.1743x; 1.0007x over previous
//
#include <hip/hip_runtime.h>

// TreeCRF belief propagation, B=2048, C=2, L=2048, BRANCH=4.
// Round-11: NO emission staging, NO em LDS. Leaf emissions (75% of traffic)
// are read once per pass -> stream from global on demand; 32 waves/CU +
// fully unrolled independent iterations hide the latency (round-5's failure
// at this pattern was 8 waves/CU + no unroll). Internal-node em re-reads hit
// L2. LDS = 4 KB alpha/pb only -> 4 barriers/block, no stage stall.
// 256-thread blocks (4 waves): waves own the 4 depth-1 subtrees; the
// 683-leaf d6 level is split across all 4 waves in both passes.
//
// Tree: parent(i) = (i-1)>>2; levels start {0,1,5,21,85,341,1365};
// internal 0..511 (node 511 has 3 children: 2045..2047), leaves 512..2047.
// Subtree k (root child 1+k): d2 i=4+4k, d3 i=20+16k (16), d4 i=84+64k (64),
// d5 i=340+256k (256; k=0 children mixed internal/leaf), d6 k=0 only.
// d6 split (i = child-1, quad-aligned): w0 [1364,1536) w1 [1536,1708)
// w2 [1708,1880) w3 [1880,2048).
// Per-edge tables precomputed into d_ws; exact 2-class LSE:
//   msg[yp] = A[yp] + l0 + ln2*log2(1 + 2^((l1-l0)*log2e) * E[yp])

constexpr int NLAB = 2048;
constexpr int NBATCH = 2048;

#define LOG2E 1.4426950408889634f
#define LN2   0.6931471805599453f

__device__ __forceinline__ float fexp2(float x) { return __builtin_amdgcn_exp2f(x); }
__device__ __forceinline__ float flog2(float x) { return __builtin_amdgcn_logf(x); }

// edge record {A0, A1, E0, E1}: A[yp]=t[yp][0], E[yp]=2^((t[yp][1]-t[yp][0])*log2e)
__global__ __launch_bounds__(256) void compact_pairs(
    const float4* __restrict__ pairs4,  // (L, L) of float4
    float4* __restrict__ up,            // pairs[parent(c)][c], [yp][yc]
    float4* __restrict__ down)          // pairs[c][parent(c)], [yc][yp]
{
    int i = blockIdx.x * 256 + threadIdx.x;
    if (i < NLAB - 1) {
        int c = i + 1, p = i >> 2;
        float4 t = pairs4[(size_t)p * NLAB + c];
        up[i] = make_float4(t.x, t.z,
                            fexp2((t.y - t.x) * LOG2E),
                            fexp2((t.w - t.z) * LOG2E));
        float4 s = pairs4[(size_t)c * NLAB + p];
        down[i] = make_float4(s.x, s.z,
                              fexp2((s.y - s.x) * LOG2E),
                              fexp2((s.w - s.z) * LOG2E));
    }
}

// up message for child index i (child = i+1); em from GLOBAL, alpha from LDS.
// AMODE: 0 leaf children, 1 mixed (alpha iff child<512), 2 all-internal.
template <int AMODE>
__device__ __forceinline__ float2 up_step(int i, bool active,
        const float* __restrict__ e0g, const float* __restrict__ e1g,
        float2* al2, const float4* __restrict__ upt) {
    const bool valid = active && (i + 1) < NLAB;
    const int c = min(i + 1, NLAB - 1);
    float l0 = e0g[c], l1 = e1g[c];
    if (AMODE == 2) { float2 a = al2[c]; l0 += a.x; l1 += a.y; }
    if (AMODE == 1) { float2 a = al2[min(c, 511)];
                      if (c < 512) { l0 += a.x; l1 += a.y; } }
    float4 t = upt[min(i, NLAB - 2)];          // {A0, A1, E0, E1}
    float eu = fexp2((l1 - l0) * LOG2E);
    float m0 = t.x + l0 + LN2 * flog2(fmaf(eu, t.z, 1.f));
    float m1 = t.y + l0 + LN2 * flog2(fmaf(eu, t.w, 1.f));
    if (!valid) { m0 = 0.f; m1 = 0.f; }
    m0 += __shfl_xor(m0, 1, 4);  m0 += __shfl_xor(m0, 2, 4);
    m1 += __shfl_xor(m1, 1, 4);  m1 += __shfl_xor(m1, 2, 4);
    if (active && (i & 3) == 0) al2[i >> 2] = make_float2(m0, m1);
    return make_float2(m0, m1);
}

// down step for node n; em from GLOBAL. DMODE: 2 internal (read alpha,
// write pb), 1 mixed (iff n<512), 0 leaf (no alpha, no pb write).
template <int DMODE>
__device__ __forceinline__ void down_step(int n, bool active,
        const float* __restrict__ e0g, const float* __restrict__ e1g,
        float2* al2, const float4* __restrict__ dnt,
        float* __restrict__ ob0, float* __restrict__ ob1) {
    const int nc = min(n, NLAB - 1);
    const int par = (nc - 1) >> 2;              // <= 511 always
    float2 pp = al2[par];                       // pb[par]
    float4 t = dnt[nc - 1];                     // {D0, D1, F0, F1}
    float eu = fexp2((pp.y - pp.x) * LOG2E);
    float m0 = t.x + pp.x + LN2 * flog2(fmaf(eu, t.z, 1.f));
    float m1 = t.y + pp.x + LN2 * flog2(fmaf(eu, t.w, 1.f));
    float pb0 = e0g[nc] + m0, pb1 = e1g[nc] + m1;
    float a0 = 0.f, a1 = 0.f;
    if (DMODE == 2) {
        float2 a = al2[nc]; a0 = a.x; a1 = a.y;
        if (active) al2[nc] = make_float2(pb0, pb1);
    }
    if (DMODE == 1) {
        float2 a = al2[min(nc, 511)];
        if (nc < 512) { a0 = a.x; a1 = a.y; }
        if (active && nc < 512) al2[nc] = make_float2(pb0, pb1);
    }
    float s0 = pb0 + a0, s1 = pb1 + a1;
    float Z = s0 + LN2 * flog2(1.f + fexp2((s1 - s0) * LOG2E));
    if (active) { ob0[n] = s0 - Z; ob1[n] = s1 - Z; }
}

__global__ __launch_bounds__(256, 8) void treecrf_kernel(
    const float* __restrict__ em_g,     // (B, 2, L)
    const float4* __restrict__ up,
    const float4* __restrict__ down,
    float* __restrict__ out)            // (B, 2, L)
{
    __shared__ float al[2 * 512];       // 4 KB: internal alpha -> pb

    const int b = blockIdx.x;
    const int tid = threadIdx.x;
    const int lane = tid & 63;
    const int w = tid >> 6;
    const int k = (w + b) & 3;          // rotated subtree assignment

    const float* __restrict__ e0g = em_g + (size_t)b * 2 * NLAB;  // class 0
    const float* __restrict__ e1g = e0g + NLAB;                   // class 1
    float2* al2 = reinterpret_cast<float2*>(al);

    // ---- d6 UP, split across ALL 4 waves (no stage, no initial barrier) ----
    {
        const int s6 = 1364 + 172 * w;          // 1364/1536/1708/1880
        const int c6 = (w == 3) ? 168 : 172;    // incl. phantom i=2047
#pragma unroll
        for (int it = 0; it < 3; ++it) {
            int i = s6 + it * 64 + lane;
            up_step<0>(i, (i - s6) < c6, e0g, e1g, al2, up);
        }
    }
    __syncthreads();                            // B1: al2[341..511] ready

    // ---- subtree UP, wave-local (deep -> shallow) ----
    if (k == 0) {
#pragma unroll
        for (int it = 0; it < 4; ++it)          // d5 children 341..596 mixed
            up_step<1>(340 + it * 64 + lane, true, e0g, e1g, al2, up);
    } else {
        const int ib = 340 + 256 * k;
#pragma unroll
        for (int it = 0; it < 4; ++it)          // d5 children all leaves
            up_step<0>(ib + it * 64 + lane, true, e0g, e1g, al2, up);
    }
    up_step<2>(84 + 64 * k + lane, true, e0g, e1g, al2, up);       // d4
    up_step<2>(20 + 16 * k + lane, lane < 16, e0g, e1g, al2, up);  // d3
    float2 acc = up_step<2>(4 + 4 * k + lane, lane < 4, e0g, e1g, al2, up); // d2
    // lanes 0..3 hold alpha[1+k] in acc (kept in registers)
    const float alpha0 = acc.x, alpha1 = acc.y;

    if (lane == 0) {                    // message (1+k) -> root
        float l0 = e0g[1 + k] + alpha0, l1 = e1g[1 + k] + alpha1;
        float4 t = up[k];               // child index i = k
        float eu = fexp2((l1 - l0) * LOG2E);
        float m0 = t.x + l0 + LN2 * flog2(fmaf(eu, t.z, 1.f));
        float m1 = t.y + l0 + LN2 * flog2(fmaf(eu, t.w, 1.f));
        al2[1 + k] = make_float2(m0, m1);   // overwrite alpha with msg
    }
    __syncthreads();                            // B2

    float* __restrict__ ob0 = out + (size_t)b * 2 * NLAB;
    float* __restrict__ ob1 = ob0 + NLAB;

    if (tid == 0) {                     // root combine
        float2 q1 = al2[1], q2 = al2[2], q3 = al2[3], q4 = al2[4];
        float ra0 = (q1.x + q2.x) + (q3.x + q4.x);
        float ra1 = (q1.y + q2.y) + (q3.y + q4.y);
        float pb0 = e0g[0], pb1 = e1g[0];
        float s0 = pb0 + ra0, s1 = pb1 + ra1;
        float Z = s0 + LN2 * flog2(1.f + fexp2((s1 - s0) * LOG2E));
        ob0[0] = s0 - Z;  ob1[0] = s1 - Z;
        al2[0] = make_float2(pb0, pb1);         // pb[0] (beta = 0)
    }
    __syncthreads();                            // B3

    // ---- subtree DOWN, wave-local (shallow -> deep) ----
    if (lane == 0) {                    // node 1+k: alpha from registers
        const int n = 1 + k;
        float2 pp = al2[0];
        float4 t = down[k];
        float eu = fexp2((pp.y - pp.x) * LOG2E);
        float m0 = t.x + pp.x + LN2 * flog2(fmaf(eu, t.z, 1.f));
        float m1 = t.y + pp.x + LN2 * flog2(fmaf(eu, t.w, 1.f));
        float pb0 = e0g[n] + m0, pb1 = e1g[n] + m1;
        al2[n] = make_float2(pb0, pb1);         // pb for d2 children
        float s0 = pb0 + alpha0, s1 = pb1 + alpha1;
        float Z = s0 + LN2 * flog2(1.f + fexp2((s1 - s0) * LOG2E));
        ob0[n] = s0 - Z;  ob1[n] = s1 - Z;
    }
    down_step<2>(5 + 4 * k + lane, lane < 4, e0g, e1g, al2, down, ob0, ob1);
    down_step<2>(21 + 16 * k + lane, lane < 16, e0g, e1g, al2, down, ob0, ob1);
    down_step<2>(85 + 64 * k + lane, true, e0g, e1g, al2, down, ob0, ob1);
    if (k == 0) {
#pragma unroll
        for (int it = 0; it < 4; ++it)          // d5 341..596 mixed
            down_step<1>(341 + it * 64 + lane, true, e0g, e1g, al2, down, ob0, ob1);
    } else {
        const int nb = 341 + 256 * k;
#pragma unroll
        for (int it = 0; it < 4; ++it)          // d5 leaves
            down_step<0>(nb + it * 64 + lane, true, e0g, e1g, al2, down, ob0, ob1);
    }
    __syncthreads();                            // B4: pb[341..511] ready

    // ---- d6 DOWN, split across ALL 4 waves ----
    {
        const int s6 = 1365 + 172 * w;          // 1365/1537/1709/1881
        const int c6 = (w == 3) ? 167 : 172;
#pragma unroll
        for (int it = 0; it < 3; ++it) {
            int n = s6 + it * 64 + lane;
            down_step<0>(n, (n - s6) < c6, e0g, e1g, al2, down, ob0, ob1);
        }
    }
}

extern "C" void kernel_launch(void* const* d_in, const int* in_sizes, int n_in,
                              void* d_out, int out_size, void* d_ws, size_t ws_size,
                              hipStream_t stream) {
    const float*  emissions = (const float*)d_in[0];
    const float4* pairs4    = (const float4*)d_in[1];
    float* outp             = (float*)d_out;

    float4* upw = (float4*)d_ws;
    float4* dnw = upw + (NLAB - 1);
    compact_pairs<<<dim3((NLAB + 255) / 256), dim3(256), 0, stream>>>(pairs4, upw, dnw);
    treecrf_kernel<<<dim3(NBATCH), dim3(256), 0, stream>>>(emissions, upw, dnw, outp);
}